// Round 1
// baseline (330.807 us; speedup 1.0000x reference)
//
#include <hip/hip_runtime.h>
#include <hip/hip_fp16.h>

#define NG  32
#define DG  64
#define NPL 64

// ---------------------------------------------------------------------------
// Pack kernel: [G][2][64][64][64] f32  ->  [G][64][64][64] half2 (c0,c1)
// ---------------------------------------------------------------------------
__global__ void pack_grids_kernel(const float* __restrict__ fg,
                                  __half2* __restrict__ pg, int total) {
    int idx = blockIdx.x * blockDim.x + threadIdx.x;
    if (idx >= total) return;
    int g = idx >> 18;                    // 64^3 = 262144 = 2^18
    int v = idx & ((1 << 18) - 1);
    const float* base = fg + ((size_t)g << 19);   // g * 2 * 2^18
    float c0 = base[v];
    float c1 = base[(1 << 18) + v];
    pg[idx] = __floats2half2_rn(c0, c1);
}

// ---------------------------------------------------------------------------
// Fused: trilinear sample (32 grids x 2ch) + 64-64-64-1 MLP, 1 thread/point
// MODE 0: packed half2 grids in d_ws.  MODE 1: raw f32 grids (ws too small).
// ---------------------------------------------------------------------------
template <int MODE>
__global__ __launch_bounds__(256)
void amrsrn_fused_kernel(const float* __restrict__ x,
                         const float* __restrict__ scales,
                         const float* __restrict__ trans,
                         const void*  __restrict__ gridsv,
                         const float* __restrict__ W0,
                         const float* __restrict__ b0,
                         const float* __restrict__ W1,
                         const float* __restrict__ b1,
                         const float* __restrict__ W2,
                         const float* __restrict__ b2,
                         float* __restrict__ out, int N)
{
    __shared__ float sW0[NPL * NPL];
    __shared__ float sW1[NPL * NPL];
    __shared__ float sW2[NPL];
    __shared__ float sb0[NPL];
    __shared__ float sb1[NPL];
    __shared__ float sS[NG * 3];
    __shared__ float sT[NG * 3];

    const int tid = threadIdx.x;
    for (int i = tid; i < NPL * NPL; i += 256) { sW0[i] = W0[i]; sW1[i] = W1[i]; }
    if (tid < NPL)   { sW2[tid] = W2[tid]; sb0[tid] = b0[tid]; sb1[tid] = b1[tid]; }
    if (tid < NG*3)  { sS[tid] = scales[tid]; sT[tid] = trans[tid]; }
    __syncthreads();

    int n = blockIdx.x * 256 + tid;
    if (n >= N) return;

    const float inv148 = (float)(1.0 / 1.48);
    float px = x[3 * n + 0];
    float py = x[3 * n + 1];
    float pz = x[3 * n + 2];

    float feat[2 * NG];

    #pragma unroll
    for (int g = 0; g < NG; ++g) {
        // replicate reference math exactly: local = (x*s + t) * INV148;
        // f = ((local + 1) * 0.5) * 63
        float lx = (px * sS[3*g+0] + sT[3*g+0]) * inv148;
        float ly = (py * sS[3*g+1] + sT[3*g+1]) * inv148;
        float lz = (pz * sS[3*g+2] + sT[3*g+2]) * inv148;
        float fx = (lx + 1.0f) * 0.5f * 63.0f;
        float fy = (ly + 1.0f) * 0.5f * 63.0f;
        float fz = (lz + 1.0f) * 0.5f * 63.0f;

        float c0 = 0.0f, c1 = 0.0f;
        // whole 2x2x2 box contributes nothing unless f in (-1, 64) per dim
        if (fx > -1.0f && fx < 64.0f &&
            fy > -1.0f && fy < 64.0f &&
            fz > -1.0f && fz < 64.0f) {
            float flx = floorf(fx), fly = floorf(fy), flz = floorf(fz);
            int x0 = (int)flx, y0 = (int)fly, z0 = (int)flz;
            float wx = fx - flx, wy = fy - fly, wz = fz - flz;

            float wxa[2], wya[2], wza[2];
            int   xia[2], yia[2], zia[2];
            wxa[0] = (x0     >= 0  && x0     < DG) ? (1.0f - wx) : 0.0f;
            wxa[1] = (x0     >= -1 && x0 + 1 < DG) ? wx          : 0.0f;
            wya[0] = (y0     >= 0  && y0     < DG) ? (1.0f - wy) : 0.0f;
            wya[1] = (y0     >= -1 && y0 + 1 < DG) ? wy          : 0.0f;
            wza[0] = (z0     >= 0  && z0     < DG) ? (1.0f - wz) : 0.0f;
            wza[1] = (z0     >= -1 && z0 + 1 < DG) ? wz          : 0.0f;
            xia[0] = min(max(x0, 0), DG - 1);     xia[1] = min(max(x0 + 1, 0), DG - 1);
            yia[0] = min(max(y0, 0), DG - 1);     yia[1] = min(max(y0 + 1, 0), DG - 1);
            zia[0] = min(max(z0, 0), DG - 1);     zia[1] = min(max(z0 + 1, 0), DG - 1);

            #pragma unroll
            for (int dz = 0; dz < 2; ++dz) {
                #pragma unroll
                for (int dy = 0; dy < 2; ++dy) {
                    int   rowoff = (zia[dz] << 12) + (yia[dy] << 6);
                    float wyz    = wya[dy] * wza[dz];
                    #pragma unroll
                    for (int dx = 0; dx < 2; ++dx) {
                        float w = wxa[dx] * wyz;
                        if (MODE == 0) {
                            const __half2* pg = (const __half2*)gridsv;
                            __half2 hv = pg[(g << 18) + rowoff + xia[dx]];
                            float2  vf = __half22float2(hv);
                            c0 = fmaf(w, vf.x, c0);
                            c1 = fmaf(w, vf.y, c1);
                        } else {
                            const float* fr = (const float*)gridsv + ((size_t)g << 19);
                            c0 = fmaf(w, fr[rowoff + xia[dx]], c0);
                            c1 = fmaf(w, fr[(1 << 18) + rowoff + xia[dx]], c1);
                        }
                    }
                }
            }
        }
        feat[2 * g + 0] = c0;
        feat[2 * g + 1] = c1;
    }

    // ---- layer 0: h1 = relu(W0 @ feat + b0) ----
    float h1[NPL];
    #pragma unroll
    for (int j = 0; j < NPL; j += 2) {
        float a0 = 0.f, a1 = 0.f, a2 = 0.f, a3 = 0.f;
        const float* r0 = &sW0[j * NPL];
        const float* r1 = &sW0[(j + 1) * NPL];
        #pragma unroll
        for (int k = 0; k < NPL; k += 2) {
            a0 = fmaf(feat[k],     r0[k],     a0);
            a1 = fmaf(feat[k + 1], r0[k + 1], a1);
            a2 = fmaf(feat[k],     r1[k],     a2);
            a3 = fmaf(feat[k + 1], r1[k + 1], a3);
        }
        h1[j]     = fmaxf((a0 + a1) + sb0[j],     0.0f);
        h1[j + 1] = fmaxf((a2 + a3) + sb0[j + 1], 0.0f);
    }

    // ---- layer 1: h2 = relu(W1 @ h1 + b1)  (reuse feat storage) ----
    #pragma unroll
    for (int j = 0; j < NPL; j += 2) {
        float a0 = 0.f, a1 = 0.f, a2 = 0.f, a3 = 0.f;
        const float* r0 = &sW1[j * NPL];
        const float* r1 = &sW1[(j + 1) * NPL];
        #pragma unroll
        for (int k = 0; k < NPL; k += 2) {
            a0 = fmaf(h1[k],     r0[k],     a0);
            a1 = fmaf(h1[k + 1], r0[k + 1], a1);
            a2 = fmaf(h1[k],     r1[k],     a2);
            a3 = fmaf(h1[k + 1], r1[k + 1], a3);
        }
        feat[j]     = fmaxf((a0 + a1) + sb1[j],     0.0f);
        feat[j + 1] = fmaxf((a2 + a3) + sb1[j + 1], 0.0f);
    }

    // ---- layer 2: out = W2 @ h2 + b2 ----
    float a0 = 0.f, a1 = 0.f;
    #pragma unroll
    for (int k = 0; k < NPL; k += 2) {
        a0 = fmaf(feat[k],     sW2[k],     a0);
        a1 = fmaf(feat[k + 1], sW2[k + 1], a1);
    }
    out[n] = (a0 + a1) + b2[0];
}

// ---------------------------------------------------------------------------
extern "C" void kernel_launch(void* const* d_in, const int* in_sizes, int n_in,
                              void* d_out, int out_size, void* d_ws, size_t ws_size,
                              hipStream_t stream) {
    const float* x  = (const float*)d_in[0];
    const float* gs = (const float*)d_in[1];
    const float* gt = (const float*)d_in[2];
    const float* fg = (const float*)d_in[3];
    const float* W0 = (const float*)d_in[4];
    const float* b0 = (const float*)d_in[5];
    const float* W1 = (const float*)d_in[6];
    const float* b1 = (const float*)d_in[7];
    const float* W2 = (const float*)d_in[8];
    const float* b2 = (const float*)d_in[9];
    float* out = (float*)d_out;

    const int N = out_size;                       // OUT = 1
    const int nblk = (N + 255) / 256;
    const size_t need = (size_t)NG * (1 << 18) * sizeof(__half2);  // 33.5 MB

    if (ws_size >= need) {
        __half2* pg = (__half2*)d_ws;
        int total = NG << 18;
        pack_grids_kernel<<<(total + 255) / 256, 256, 0, stream>>>(fg, pg, total);
        amrsrn_fused_kernel<0><<<nblk, 256, 0, stream>>>(
            x, gs, gt, pg, W0, b0, W1, b1, W2, b2, out, N);
    } else {
        amrsrn_fused_kernel<1><<<nblk, 256, 0, stream>>>(
            x, gs, gt, fg, W0, b0, W1, b1, W2, b2, out, N);
    }
}